// Round 5
// baseline (55.101 us; speedup 1.0000x reference)
//
#include <hip/hip_runtime.h>

#define S_LEN 4096
#define D_K   128

// log2(10000)/64 : inv_freq(j) = 2^(-j * KSC)
#define KSC      0.20762050593046f
#define INV_2PI  0.15915494309189535f

// Native clang vector type — required by __builtin_nontemporal_load/store
// (HIP's float4 is a class and is rejected).
typedef float f32x4 __attribute__((ext_vector_type(4)));

__device__ __forceinline__ f32x4 rot2(f32x4 xv, float c0, float s0, float c1, float s1) {
    f32x4 o;
    o.x = c0 * xv.x - s0 * xv.y;
    o.y = s0 * xv.x + c0 * xv.y;
    o.z = c1 * xv.z - s1 * xv.w;
    o.w = s1 * xv.z + c1 * xv.w;
    return o;
}

// Fused RoPE: (c,s) computed analytically once per thread (loop-invariant),
// then a 4x-unrolled non-temporal streaming loop.
// Requires nthreads % (32 * S_LEN) == 0 (host guarantees 524288 threads).
__global__ __launch_bounds__(256)
void rope_fused_kernel(const f32x4* __restrict__ x,
                       const int* __restrict__ token_positions,
                       f32x4* __restrict__ out,
                       int total4) {
    int tid      = blockIdx.x * blockDim.x + threadIdx.x;
    int nthreads = gridDim.x * blockDim.x;

    int d4 = tid & 31;                 // float4 index within the 128-dim head
    int s  = (tid >> 5) & (S_LEN - 1); // sequence position (loop-invariant)

    float fp = (float)token_positions[s];
    float j0 = (float)(2 * d4);

    // angle in revolutions, fract-reduced for v_sin/v_cos
    float e0 = __builtin_amdgcn_exp2f(-j0 * KSC);
    float e1 = __builtin_amdgcn_exp2f(-(j0 + 1.0f) * KSC);
    float r0 = fp * e0 * INV_2PI;  r0 -= floorf(r0);
    float r1 = fp * e1 * INV_2PI;  r1 -= floorf(r1);

    float s0, c0, s1, c1;
    asm("v_sin_f32 %0, %1" : "=v"(s0) : "v"(r0));
    asm("v_cos_f32 %0, %1" : "=v"(c0) : "v"(r0));
    asm("v_sin_f32 %0, %1" : "=v"(s1) : "v"(r1));
    asm("v_cos_f32 %0, %1" : "=v"(c1) : "v"(r1));

    int idx = tid;
    // Main: 4x unroll, independent non-temporal loads clustered for MLP.
    for (; idx + 3 * nthreads < total4; idx += 4 * nthreads) {
        f32x4 a = __builtin_nontemporal_load(&x[idx]);
        f32x4 b = __builtin_nontemporal_load(&x[idx + nthreads]);
        f32x4 c = __builtin_nontemporal_load(&x[idx + 2 * nthreads]);
        f32x4 d = __builtin_nontemporal_load(&x[idx + 3 * nthreads]);
        __builtin_nontemporal_store(rot2(a, c0, s0, c1, s1), &out[idx]);
        __builtin_nontemporal_store(rot2(b, c0, s0, c1, s1), &out[idx + nthreads]);
        __builtin_nontemporal_store(rot2(c, c0, s0, c1, s1), &out[idx + 2 * nthreads]);
        __builtin_nontemporal_store(rot2(d, c0, s0, c1, s1), &out[idx + 3 * nthreads]);
    }
    for (; idx < total4; idx += nthreads) {
        f32x4 a = __builtin_nontemporal_load(&x[idx]);
        __builtin_nontemporal_store(rot2(a, c0, s0, c1, s1), &out[idx]);
    }
}

// Generic fallback (trig per iteration) for unexpected sizes. Same math.
__global__ __launch_bounds__(256)
void rope_fused_generic_kernel(const f32x4* __restrict__ x,
                               const int* __restrict__ token_positions,
                               f32x4* __restrict__ out,
                               int total4) {
    int stride = gridDim.x * blockDim.x;
    for (int idx = blockIdx.x * blockDim.x + threadIdx.x; idx < total4; idx += stride) {
        int d4 = idx & 31;
        int s  = (idx >> 5) & (S_LEN - 1);
        float fp = (float)token_positions[s];
        float j0 = (float)(2 * d4);
        float e0 = __builtin_amdgcn_exp2f(-j0 * KSC);
        float e1 = __builtin_amdgcn_exp2f(-(j0 + 1.0f) * KSC);
        float r0 = fp * e0 * INV_2PI;  r0 -= floorf(r0);
        float r1 = fp * e1 * INV_2PI;  r1 -= floorf(r1);
        float s0, c0, s1, c1;
        asm("v_sin_f32 %0, %1" : "=v"(s0) : "v"(r0));
        asm("v_cos_f32 %0, %1" : "=v"(c0) : "v"(r0));
        asm("v_sin_f32 %0, %1" : "=v"(s1) : "v"(r1));
        asm("v_cos_f32 %0, %1" : "=v"(c1) : "v"(r1));
        f32x4 xv = x[idx];
        out[idx] = rot2(xv, c0, s0, c1, s1);
    }
}

extern "C" void kernel_launch(void* const* d_in, const int* in_sizes, int n_in,
                              void* d_out, int out_size, void* d_ws, size_t ws_size,
                              hipStream_t stream) {
    const float* x   = (const float*)d_in[0];
    const int*   pos = (const int*)d_in[1];   // integer inputs arrive as int32
    float*       out = (float*)d_out;

    int total4 = out_size / 4;

    // 2048 blocks x 256 threads = 524288; multiple of 32*S_LEN so (d4, s)
    // are loop-invariant per thread in the fused kernel.
    const int blocks = 2048, tpb = 256;
    if (((long long)blocks * tpb) % (32 * S_LEN) == 0) {
        rope_fused_kernel<<<blocks, tpb, 0, stream>>>((const f32x4*)x, pos,
                                                      (f32x4*)out, total4);
    } else {
        rope_fused_generic_kernel<<<blocks, tpb, 0, stream>>>((const f32x4*)x, pos,
                                                              (f32x4*)out, total4);
    }
}

// Round 6
// 45.816 us; speedup vs baseline: 1.2027x; 1.2027x over previous
//
#include <hip/hip_runtime.h>

#define S_LEN 4096
#define D_K   128

// log2(10000)/64 : inv_freq(j) = 2^(-j * KSC)
#define KSC      0.20762050593046f
#define INV_2PI  0.15915494309189535f

// Fused RoPE: compute (c,s) analytically, once per thread (loop-invariant),
// then pure streaming float4 load/rotate/store.
//
// Loop-invariance of (d4, s) requires nthreads % (32 * S_LEN) == 0,
// guaranteed by the host launch config (2048 blocks x 256 = 524288 = 4*131072).
__global__ __launch_bounds__(256)
void rope_fused_kernel(const float4* __restrict__ x,
                       const int* __restrict__ token_positions,
                       float4* __restrict__ out,
                       int total4) {
    int tid      = blockIdx.x * blockDim.x + threadIdx.x;
    int nthreads = gridDim.x * blockDim.x;

    int d4 = tid & 31;                 // float4 index within the 128-dim head
    int s  = (tid >> 5) & (S_LEN - 1); // sequence position (invariant across iters)

    float fp = (float)token_positions[s];
    float j0 = (float)(2 * d4);

    // angle in revolutions: p * theta^(-j/64) / (2*pi), fract-reduced for v_sin/v_cos
    float e0 = __builtin_amdgcn_exp2f(-j0 * KSC);
    float e1 = __builtin_amdgcn_exp2f(-(j0 + 1.0f) * KSC);
    float r0 = fp * e0 * INV_2PI;  r0 -= floorf(r0);
    float r1 = fp * e1 * INV_2PI;  r1 -= floorf(r1);

    float s0, c0, s1, c1;
    asm("v_sin_f32 %0, %1" : "=v"(s0) : "v"(r0));
    asm("v_cos_f32 %0, %1" : "=v"(c0) : "v"(r0));
    asm("v_sin_f32 %0, %1" : "=v"(s1) : "v"(r1));
    asm("v_cos_f32 %0, %1" : "=v"(c1) : "v"(r1));

    for (int idx = tid; idx < total4; idx += nthreads) {
        float4 xv = x[idx];
        float4 o;
        o.x = c0 * xv.x - s0 * xv.y;
        o.y = s0 * xv.x + c0 * xv.y;
        o.z = c1 * xv.z - s1 * xv.w;
        o.w = s1 * xv.z + c1 * xv.w;
        out[idx] = o;
    }
}

// Generic fallback (trig per iteration) in case the grid/stride invariant
// can't be satisfied for an unexpected out_size. Same math.
__global__ __launch_bounds__(256)
void rope_fused_generic_kernel(const float4* __restrict__ x,
                               const int* __restrict__ token_positions,
                               float4* __restrict__ out,
                               int total4) {
    int stride = gridDim.x * blockDim.x;
    for (int idx = blockIdx.x * blockDim.x + threadIdx.x; idx < total4; idx += stride) {
        int d4 = idx & 31;
        int s  = (idx >> 5) & (S_LEN - 1);
        float fp = (float)token_positions[s];
        float j0 = (float)(2 * d4);
        float e0 = __builtin_amdgcn_exp2f(-j0 * KSC);
        float e1 = __builtin_amdgcn_exp2f(-(j0 + 1.0f) * KSC);
        float r0 = fp * e0 * INV_2PI;  r0 -= floorf(r0);
        float r1 = fp * e1 * INV_2PI;  r1 -= floorf(r1);
        float s0, c0, s1, c1;
        asm("v_sin_f32 %0, %1" : "=v"(s0) : "v"(r0));
        asm("v_cos_f32 %0, %1" : "=v"(c0) : "v"(r0));
        asm("v_sin_f32 %0, %1" : "=v"(s1) : "v"(r1));
        asm("v_cos_f32 %0, %1" : "=v"(c1) : "v"(r1));
        float4 xv = x[idx];
        float4 o;
        o.x = c0 * xv.x - s0 * xv.y;
        o.y = s0 * xv.x + c0 * xv.y;
        o.z = c1 * xv.z - s1 * xv.w;
        o.w = s1 * xv.z + c1 * xv.w;
        out[idx] = o;
    }
}

extern "C" void kernel_launch(void* const* d_in, const int* in_sizes, int n_in,
                              void* d_out, int out_size, void* d_ws, size_t ws_size,
                              hipStream_t stream) {
    const float* x   = (const float*)d_in[0];
    const int*   pos = (const int*)d_in[1];   // harness passes integer inputs as int32
    float*       out = (float*)d_out;

    int total4 = out_size / 4;

    // 2048 blocks x 256 threads = 524288 threads; stride is a multiple of
    // 32*S_LEN so (d4, s) are loop-invariant per thread in the fused kernel.
    const int blocks = 2048, tpb = 256;
    if (((long long)blocks * tpb) % (32 * S_LEN) == 0) {
        rope_fused_kernel<<<blocks, tpb, 0, stream>>>((const float4*)x, pos,
                                                      (float4*)out, total4);
    } else {
        rope_fused_generic_kernel<<<blocks, tpb, 0, stream>>>((const float4*)x, pos,
                                                              (float4*)out, total4);
    }
}